// Round 3
// baseline (1899.798 us; speedup 1.0000x reference)
//
#include <hip/hip_runtime.h>
#include <cmath>

// Problem constants (fixed by the reference)
#define B_  32
#define S_  196
#define D_  768
#define H_  12
#define E_  8
#define F_  3072
#define DH_ 64
#define T_  (B_ * S_)   // 6272 tokens; 6272 % 128 == 0

typedef unsigned short ushort_t;
typedef short   s16x8   __attribute__((ext_vector_type(8)));
typedef __bf16  bf16x8_t __attribute__((ext_vector_type(8)));
typedef float   f32x4   __attribute__((ext_vector_type(4)));

// 16-byte MFMA A/B fragment; converts to whichever vector type the builtin wants.
struct ABFrag {
    unsigned int r[4];
    __device__ operator s16x8()    const { return __builtin_bit_cast(s16x8, *this); }
    __device__ operator bf16x8_t() const { return __builtin_bit_cast(bf16x8_t, *this); }
};

__device__ __forceinline__ ushort_t f2bf(float f) {
    unsigned int x = __float_as_uint(f);
    return (ushort_t)((x + 0x7fffu + ((x >> 16) & 1u)) >> 16);   // RNE
}

// async global->LDS, 16B per lane (dest wave-uniform base, HW adds lane*16)
__device__ __forceinline__ void glds16(const void* g, void* l) {
    __builtin_amdgcn_global_load_lds((const __attribute__((address_space(1))) void*)g,
                                     (__attribute__((address_space(3))) void*)l,
                                     16, 0, 0);
}

// native fp32 atomic add (agent scope -> global_atomic_add_f32, no CAS loop)
__device__ __forceinline__ void atomAddF(float* p, float v) {
    __hip_atomic_fetch_add(p, v, __ATOMIC_RELAXED, __HIP_MEMORY_SCOPE_AGENT);
}

// ---------------------------------------------------------------------------
// bf16 MFMA GEMM (m97 structure): C = A @ Bt^T.  128x128 tile, BK=32,
// 256 threads (4 waves 2x2), wave = 64x64 = 4x4 16x16x32 frags.
// K is the per-launch CHUNK length (blockIdx.z selects chunk at z*K);
// lda/ldb are full row strides of A/Bt.
// EPI 0: fp32 out +bias.
// EPI 1: bf16 out, +bias then exact GELU.
// EPI 2: atomic accumulate: C += gates[row*E+expert]*(acc + (z==0)*bias)
// EPI 3: fused QKV: col segment s=col/768 selects A{0,1,2} and C{0,1,2}.
// ---------------------------------------------------------------------------
template<int EPI>
__global__ __launch_bounds__(256)
void gemm_bt(const ushort_t* __restrict__ A0, const ushort_t* __restrict__ A1,
             const ushort_t* __restrict__ A2, const ushort_t* __restrict__ Bt,
             const float* __restrict__ bias,
             float* __restrict__ C0, float* __restrict__ C1,
             float* __restrict__ C2, ushort_t* __restrict__ Cb,
             int M, int N, int K, int lda, int ldb,
             const float* __restrict__ gates, int expert)
{
    __shared__ ushort_t Alds[128 * 32];
    __shared__ ushort_t Blds[128 * 32];

    const int tid = threadIdx.x;
    const int w  = tid >> 6, l = tid & 63;
    const int wr = w >> 1,  wc = w & 1;
    const int rg = l >> 4,  fr = l & 15;
    const int brow = blockIdx.y * 128;
    const int bcol = blockIdx.x * 128;
    const int koff = blockIdx.z * K;

    // segment select (block-uniform: 768 % 128 == 0)
    const int seg = (EPI == 3) ? (bcol / 768) : 0;
    const ushort_t* A = (EPI == 3) ? (seg == 0 ? A0 : seg == 1 ? A1 : A2) : A0;
    float* Cf         = (EPI == 3) ? (seg == 0 ? C0 : seg == 1 ? C1 : C2) : C0;
    const int ldc     = (EPI == 3) ? 768 : N;
    const int ccol0   = bcol - seg * 768;   // col base in output

    const int srow = tid >> 2;            // 0..63
    const int scol = (tid & 3) << 3;      // 0,8,16,24
    const ushort_t* gA = A  + (size_t)(brow + srow) * lda + koff + scol;
    const ushort_t* gB = Bt + (size_t)(bcol + srow) * ldb + koff + scol;
    ushort_t* lA = &Alds[w * 512];
    ushort_t* lB = &Blds[w * 512];

    f32x4 acc[4][4] = {};
    const int aoff = (wr * 64 + fr) * 32 + rg * 8;
    const int boff = (wc * 64 + fr) * 32 + rg * 8;

    for (int k0 = 0; k0 < K; k0 += 32) {
        if (k0) __syncthreads();
        glds16(gA,                    lA);
        glds16(gA + (size_t)64 * lda, lA + 2048);
        glds16(gB,                    lB);
        glds16(gB + (size_t)64 * ldb, lB + 2048);
        gA += 32; gB += 32;
        __syncthreads();

        ABFrag af[4], bfr[4];
        #pragma unroll
        for (int m = 0; m < 4; ++m) af[m]  = *(const ABFrag*)&Alds[aoff + m * 512];
        #pragma unroll
        for (int n = 0; n < 4; ++n) bfr[n] = *(const ABFrag*)&Blds[boff + n * 512];
        #pragma unroll
        for (int m = 0; m < 4; ++m)
            #pragma unroll
            for (int n = 0; n < 4; ++n)
                acc[m][n] = __builtin_amdgcn_mfma_f32_16x16x32_bf16(
                                af[m], bfr[n], acc[m][n], 0, 0, 0);
    }

    // D frag: col = lane&15, row = (lane>>4)*4 + reg
    #pragma unroll
    for (int m = 0; m < 4; ++m) {
        #pragma unroll
        for (int n = 0; n < 4; ++n) {
            const int cg  = bcol + wc * 64 + n * 16 + fr;    // global col (bias)
            const int col = ccol0 + wc * 64 + n * 16 + fr;   // output col
            float bv = bias[cg];
            if (EPI == 2 && blockIdx.z != 0) bv = 0.f;
            #pragma unroll
            for (int j = 0; j < 4; ++j) {
                const int row = brow + wr * 64 + m * 16 + rg * 4 + j;
                float vv = acc[m][n][j] + bv;
                if (EPI == 1) {
                    vv = 0.5f * vv * (1.0f + erff(vv * 0.70710678118654752f));
                    Cb[(size_t)row * N + col] = f2bf(vv);
                } else if (EPI == 2) {
                    atomAddF(&Cf[(size_t)row * ldc + col],
                             gates[(size_t)row * E_ + expert] * vv);
                } else {
                    Cf[(size_t)row * ldc + col] = vv;
                }
            }
        }
    }
}

// ---------------------------------------------------------------------------
// fp32 -> bf16 linear convert (float4 per thread)
// ---------------------------------------------------------------------------
__global__ __launch_bounds__(256)
void convert_bf16(const float* __restrict__ in, ushort_t* __restrict__ out)
{
    const int i = blockIdx.x * 256 + threadIdx.x;
    float4 v = ((const float4*)in)[i];
    ushort4 o;
    o.x = f2bf(v.x); o.y = f2bf(v.y); o.z = f2bf(v.z); o.w = f2bf(v.w);
    ((ushort4*)out)[i] = o;
}

// ---------------------------------------------------------------------------
// fp32 [R][C] -> bf16 [C][R] transpose (R, C multiples of 64)
// ---------------------------------------------------------------------------
__global__ __launch_bounds__(256)
void transpose_to_bf16(const float* __restrict__ in, ushort_t* __restrict__ out,
                       int R, int C)
{
    __shared__ float tile[64][65];
    const int bc = blockIdx.x * 64;
    const int br = blockIdx.y * 64;
    const int lr = threadIdx.x >> 4;
    const int lc = (threadIdx.x & 15) << 2;
    #pragma unroll
    for (int i = 0; i < 64; i += 16) {
        float4 v = *(const float4*)&in[(size_t)(br + lr + i) * C + bc + lc];
        tile[lr + i][lc + 0] = v.x; tile[lr + i][lc + 1] = v.y;
        tile[lr + i][lc + 2] = v.z; tile[lr + i][lc + 3] = v.w;
    }
    __syncthreads();
    #pragma unroll
    for (int i = 0; i < 64; i += 16) {
        const int orow = lr + i;
        ushort4 o;
        o.x = f2bf(tile[lc + 0][orow]);
        o.y = f2bf(tile[lc + 1][orow]);
        o.z = f2bf(tile[lc + 2][orow]);
        o.w = f2bf(tile[lc + 3][orow]);
        *(ushort4*)&out[(size_t)(bc + orow) * R + br + lc] = o;
    }
}

// ---------------------------------------------------------------------------
// Attention, single-pass online softmax. One block per (b,h); K in LDS;
// per-thread q-row in registers; V rows broadcast-read from global (L2-hot).
// No global scratch.
// ---------------------------------------------------------------------------
__global__ __launch_bounds__(256)
void attn_kernel(const float* __restrict__ qh, const float* __restrict__ kh,
                 const float* __restrict__ vh, float* __restrict__ ctx)
{
    __shared__ float Ks[S_ * DH_];   // 50,176 B
    const int bh = blockIdx.x;
    const int b  = bh / H_;
    const int h  = bh % H_;
    const int tid = threadIdx.x;

    for (int i = tid; i < S_ * 16; i += 256) {           // S_*16 float4s
        const int s = i >> 4, d4 = i & 15;
        ((float4*)Ks)[s * 16 + d4] =
            *(const float4*)&kh[((size_t)(b * S_ + s)) * D_ + h * DH_ + d4 * 4];
    }
    __syncthreads();
    if (tid >= S_) return;

    float qf[DH_];
    const float* qrow = qh + ((size_t)(b * S_ + tid)) * D_ + h * DH_;
    #pragma unroll
    for (int d = 0; d < DH_; d += 4) {
        float4 v4 = *(const float4*)(qrow + d);
        qf[d+0] = v4.x * 0.125f; qf[d+1] = v4.y * 0.125f;   // fold 1/sqrt(64)
        qf[d+2] = v4.z * 0.125f; qf[d+3] = v4.w * 0.125f;
    }

    float m = -1e30f, lsum = 0.f;
    float acc[DH_] = {};
    const float* vbase = vh + ((size_t)b * S_) * D_ + h * DH_;

    for (int k = 0; k < S_; ++k) {
        const float* kr = &Ks[k * DH_];
        float s0 = 0.f, s1 = 0.f, s2 = 0.f, s3 = 0.f;
        #pragma unroll
        for (int d = 0; d < DH_; d += 4) {
            s0 = fmaf(qf[d+0], kr[d+0], s0);
            s1 = fmaf(qf[d+1], kr[d+1], s1);
            s2 = fmaf(qf[d+2], kr[d+2], s2);
            s3 = fmaf(qf[d+3], kr[d+3], s3);
        }
        const float sv = (s0 + s1) + (s2 + s3);
        if (sv > m) {                       // rare after warm-up
            const float alpha = __expf(m - sv);
            lsum *= alpha;
            #pragma unroll
            for (int d = 0; d < DH_; ++d) acc[d] *= alpha;
            m = sv;
        }
        const float p = __expf(sv - m);
        lsum += p;
        const float* vr = vbase + (size_t)k * D_;
        #pragma unroll
        for (int d = 0; d < DH_; d += 4) {
            float4 v4 = *(const float4*)(vr + d);
            acc[d+0] = fmaf(p, v4.x, acc[d+0]);
            acc[d+1] = fmaf(p, v4.y, acc[d+1]);
            acc[d+2] = fmaf(p, v4.z, acc[d+2]);
            acc[d+3] = fmaf(p, v4.w, acc[d+3]);
        }
    }
    const float inv = 1.f / lsum;
    float* crow = ctx + ((size_t)(b * S_ + tid)) * D_ + h * DH_;
    #pragma unroll
    for (int d = 0; d < DH_; ++d) crow[d] = acc[d] * inv;
}

// ---------------------------------------------------------------------------
// Residual + LayerNorm (+ optional zero of another buffer's same row)
// ---------------------------------------------------------------------------
__device__ __forceinline__ float block_sum(float v, float* red)
{
    __syncthreads();
    const int lane = threadIdx.x & 63;
    const int wid  = threadIdx.x >> 6;
    #pragma unroll
    for (int off = 32; off > 0; off >>= 1) v += __shfl_down(v, off);
    if (lane == 0) red[wid] = v;
    __syncthreads();
    return red[0] + red[1] + red[2] + red[3];
}

__global__ __launch_bounds__(256)
void ln_kernel(const float* __restrict__ a, const float* __restrict__ bres,
               const float* __restrict__ g, const float* __restrict__ beta,
               float* __restrict__ out, float* __restrict__ zt)
{
    __shared__ float red[4];
    const int t   = blockIdx.x;
    const int tid = threadIdx.x;
    const float* ar = a    + (size_t)t * D_;
    const float* br = bres + (size_t)t * D_;

    float vals[3];
    float s = 0.f;
    #pragma unroll
    for (int i = 0; i < 3; ++i) {
        const int d = tid + i * 256;
        const float x = ar[d] + br[d];
        vals[i] = x;
        s += x;
        if (zt) zt[(size_t)t * D_ + d] = 0.f;
    }
    s = block_sum(s, red);
    const float mu = s * (1.f / D_);
    float qv = 0.f;
    #pragma unroll
    for (int i = 0; i < 3; ++i) { const float dv = vals[i] - mu; qv += dv * dv; }
    qv = block_sum(qv, red);
    const float rstd = rsqrtf(qv * (1.f / D_) + 1e-5f);
    #pragma unroll
    for (int i = 0; i < 3; ++i) {
        const int d = tid + i * 256;
        out[(size_t)t * D_ + d] = (vals[i] - mu) * rstd * g[d] + beta[d];
    }
}

// ---------------------------------------------------------------------------
// Gate: gates = softmax(x @ Wg + bg). One wave per token.
// ---------------------------------------------------------------------------
__global__ __launch_bounds__(256)
void gate_kernel(const float* __restrict__ x, const float* __restrict__ Wg,
                 const float* __restrict__ bg, float* __restrict__ gates)
{
    const int lane = threadIdx.x & 63;
    const int wid  = threadIdx.x >> 6;
    const int t = blockIdx.x * 4 + wid;
    const float* xr = x + (size_t)t * D_;

    float accv[E_];
    #pragma unroll
    for (int e = 0; e < E_; ++e) accv[e] = 0.f;
    for (int d = lane; d < D_; d += 64) {
        const float xv = xr[d];
        const float* wr = Wg + (size_t)d * E_;
        #pragma unroll
        for (int e = 0; e < E_; ++e) accv[e] = fmaf(xv, wr[e], accv[e]);
    }
    #pragma unroll
    for (int e = 0; e < E_; ++e) {
        #pragma unroll
        for (int off = 32; off > 0; off >>= 1)
            accv[e] += __shfl_down(accv[e], off);
    }
    if (lane == 0) {
        float mx = -1e30f;
        #pragma unroll
        for (int e = 0; e < E_; ++e) { accv[e] += bg[e]; mx = fmaxf(mx, accv[e]); }
        float lsum = 0.f;
        #pragma unroll
        for (int e = 0; e < E_; ++e) { const float p = expf(accv[e] - mx); accv[e] = p; lsum += p; }
        const float inv = 1.f / lsum;
        #pragma unroll
        for (int e = 0; e < E_; ++e) gates[(size_t)t * E_ + e] = accv[e] * inv;
    }
}

__global__ void concat3_kernel(const float* __restrict__ a, const float* __restrict__ b,
                               const float* __restrict__ c, float* __restrict__ o)
{
    const int i = blockIdx.x * 256 + threadIdx.x;
    if (i < 768)       o[i] = a[i];
    else if (i < 1536) o[i] = b[i - 768];
    else if (i < 2304) o[i] = c[i - 1536];
}

// ---------------------------------------------------------------------------
// Orchestration. Workspace (float offsets), peak ~139.4 MB:
//   [0,TD)       qh -> attnout -> {xb (bf16, first TD elems), gates (+TD/2)}
//   [TD,2TD)     kh -> x (persists)
//   [2TD,4TD)    vh, ctx -> h (T*F bf16 = exactly 2TD floats)
//   [4TD,5TD)    moe accumulator
//   [5TD,6.5TD)  qb,kb,vb (bf16) -> ctxb reuses qb slot
//   [6.5TD,...)  wqkvt(3D^2) | wot(D^2) | bias_cat(2304 f) | w1t | w2t
// ---------------------------------------------------------------------------
extern "C" void kernel_launch(void* const* d_in, const int* in_sizes, int n_in,
                              void* d_out, int out_size, void* d_ws, size_t ws_size,
                              hipStream_t stream)
{
    const float* q    = (const float*)d_in[0];
    const float* k    = (const float*)d_in[1];
    const float* v    = (const float*)d_in[2];
    const float* Wq   = (const float*)d_in[3];
    const float* bq   = (const float*)d_in[4];
    const float* Wk   = (const float*)d_in[5];
    const float* bk   = (const float*)d_in[6];
    const float* Wv   = (const float*)d_in[7];
    const float* bv   = (const float*)d_in[8];
    const float* Wo   = (const float*)d_in[9];
    const float* bo   = (const float*)d_in[10];
    const float* ln1g = (const float*)d_in[11];
    const float* ln1b = (const float*)d_in[12];
    const float* ln2g = (const float*)d_in[13];
    const float* ln2b = (const float*)d_in[14];
    const float* Wg   = (const float*)d_in[15];
    const float* bg   = (const float*)d_in[16];
    const float* W1   = (const float*)d_in[17];
    const float* b1   = (const float*)d_in[18];
    const float* W2   = (const float*)d_in[19];
    const float* b2   = (const float*)d_in[20];
    float* out = (float*)d_out;
    float* ws  = (float*)d_ws;

    const size_t TD = (size_t)T_ * D_;                 // 4,816,896
    const size_t DD = (size_t)D_ * D_;                 // 589,824
    const size_t DF = (size_t)D_ * F_;                 // 2,359,296

    float* qh      = ws;                               // -> attnout
    float* x       = ws + TD;                          // kh -> x
    float* kh      = x;
    float* vh      = ws + 2 * TD;
    float* ctx     = ws + 3 * TD;
    float* moe     = ws + 4 * TD;
    ushort_t* hb   = (ushort_t*)(ws + 2 * TD);         // T*F bf16 over vh+ctx
    ushort_t* xb   = (ushort_t*)qh;                    // after attnout dead
    float* gates   = qh + TD / 2;
    float* attnout = qh;

    ushort_t* qb   = (ushort_t*)(ws + 5 * TD);
    ushort_t* kb   = qb + TD;
    ushort_t* vb   = kb + TD;
    ushort_t* ctxb = qb;                               // qb dead after QKV

    ushort_t* wqkvt = (ushort_t*)(ws + 6 * TD + TD / 2);
    ushort_t* wot   = wqkvt + 3 * DD;
    float*    bcat  = (float*)(wot + DD);
    ushort_t* w1t   = (ushort_t*)(bcat + 2304);
    ushort_t* w2t   = w1t + DF;

    const dim3 blk(256);
    const int  cgrid = (int)(TD / 1024);               // convert grid (exact)

    // --- Phase 0: weight prep ---
    concat3_kernel<<<dim3(9), blk, 0, stream>>>(bq, bk, bv, bcat);
    transpose_to_bf16<<<dim3(D_/64, D_/64), blk, 0, stream>>>(Wq, wqkvt,          D_, D_);
    transpose_to_bf16<<<dim3(D_/64, D_/64), blk, 0, stream>>>(Wk, wqkvt + DD,     D_, D_);
    transpose_to_bf16<<<dim3(D_/64, D_/64), blk, 0, stream>>>(Wv, wqkvt + 2 * DD, D_, D_);
    transpose_to_bf16<<<dim3(D_/64, D_/64), blk, 0, stream>>>(Wo, wot,            D_, D_);

    // --- Phase 1: inputs -> bf16, fused QKV GEMM ---
    convert_bf16<<<cgrid, blk, 0, stream>>>(q, qb);
    convert_bf16<<<cgrid, blk, 0, stream>>>(k, kb);
    convert_bf16<<<cgrid, blk, 0, stream>>>(v, vb);
    gemm_bt<3><<<dim3(18, 49), blk, 0, stream>>>(qb, kb, vb, wqkvt, bcat,
                                                 qh, kh, vh, nullptr,
                                                 T_, 2304, D_, D_, D_, nullptr, 0);

    // --- Phase 2: attention (no scratch) ---
    attn_kernel<<<dim3(B_ * H_), blk, 0, stream>>>(qh, kh, vh, ctx);

    // --- Phase 3: Wo projection, residual + LN1 (+ zero moe) ---
    convert_bf16<<<cgrid, blk, 0, stream>>>(ctx, ctxb);
    gemm_bt<0><<<dim3(6, 49), blk, 0, stream>>>(ctxb, nullptr, nullptr, wot, bo,
                                                attnout, nullptr, nullptr, nullptr,
                                                T_, D_, D_, D_, D_, nullptr, 0);
    ln_kernel<<<dim3(T_), blk, 0, stream>>>(q, attnout, ln1g, ln1b, x, moe);

    // --- Phase 4: gating, x -> bf16 ---
    gate_kernel<<<dim3(T_ / 4), blk, 0, stream>>>(x, Wg, bg, gates);
    convert_bf16<<<cgrid, blk, 0, stream>>>(x, xb);

    // --- Phase 5: MoE experts (W2 split-K x4, atomic accumulate) ---
    for (int e = 0; e < E_; ++e) {
        transpose_to_bf16<<<dim3(F_/64, D_/64), blk, 0, stream>>>(
            W1 + (size_t)e * DF, w1t, D_, F_);
        transpose_to_bf16<<<dim3(D_/64, F_/64), blk, 0, stream>>>(
            W2 + (size_t)e * DF, w2t, F_, D_);
        gemm_bt<1><<<dim3(24, 49), blk, 0, stream>>>(xb, nullptr, nullptr, w1t,
                                                     b1 + (size_t)e * F_,
                                                     nullptr, nullptr, nullptr, hb,
                                                     T_, F_, D_, D_, D_, nullptr, 0);
        gemm_bt<2><<<dim3(6, 49, 4), blk, 0, stream>>>(hb, nullptr, nullptr, w2t,
                                                       b2 + (size_t)e * D_,
                                                       moe, nullptr, nullptr, nullptr,
                                                       T_, D_, 768, F_, F_, gates, e);
    }

    // --- Phase 6: residual + LN2 -> output ---
    ln_kernel<<<dim3(T_), blk, 0, stream>>>(x, moe, ln2g, ln2b, out, nullptr);
}

// Round 6
// 1631.272 us; speedup vs baseline: 1.1646x; 1.1646x over previous
//
#include <hip/hip_runtime.h>
#include <cmath>

// Problem constants (fixed by the reference)
#define B_  32
#define S_  196
#define D_  768
#define H_  12
#define E_  8
#define F_  3072
#define DH_ 64
#define T_  (B_ * S_)   // 6272 tokens; 6272 % 128 == 0

typedef unsigned short ushort_t;
typedef short   s16x8   __attribute__((ext_vector_type(8)));
typedef __bf16  bf16x8_t __attribute__((ext_vector_type(8)));
typedef float   f32x4   __attribute__((ext_vector_type(4)));

// 16-byte MFMA A/B fragment; converts to whichever vector type the builtin wants.
struct ABFrag {
    unsigned int r[4];
    __device__ operator s16x8()    const { return __builtin_bit_cast(s16x8, *this); }
    __device__ operator bf16x8_t() const { return __builtin_bit_cast(bf16x8_t, *this); }
};

__device__ __forceinline__ ushort_t f2bf(float f) {
    unsigned int x = __float_as_uint(f);
    return (ushort_t)((x + 0x7fffu + ((x >> 16) & 1u)) >> 16);   // RNE
}

// async global->LDS, 16B per lane (dest wave-uniform base, HW adds lane*16)
__device__ __forceinline__ void glds16(const void* g, void* l) {
    __builtin_amdgcn_global_load_lds((const __attribute__((address_space(1))) void*)g,
                                     (__attribute__((address_space(3))) void*)l,
                                     16, 0, 0);
}

// native fp32 atomic add (agent scope -> global_atomic_add_f32, no CAS loop)
__device__ __forceinline__ void atomAddF(float* p, float v) {
    __hip_atomic_fetch_add(p, v, __ATOMIC_RELAXED, __HIP_MEMORY_SCOPE_AGENT);
}

// ---------------------------------------------------------------------------
// bf16 MFMA GEMM (m97 structure): C = A @ Bt^T.  128x128 tile, BK=32,
// 256 threads (4 waves 2x2), wave = 64x64 = 4x4 16x16x32 frags.
// lda/ldb are row strides of A/Bt (bf16 elems).
// EPI 0: fp32 out + bias                       (z unused)
// EPI 1: batched W1: e=z; B+=e*strideB; bf16 out (e? Cb1:Cb0) = GELU(acc+bias)
// EPI 2: batched W2 split-K2: e=z>>1, kchunk=z&1; A=(e?A1:A0); B+=e*strideB;
//        koff=kchunk*K; atomic C0 += gates[row,eb+e]*(acc + (kchunk==0)*bias)
// EPI 3: fused QKV: col segment s=bcol/768 selects A{0,1,2}, C{0,1,2}
// ---------------------------------------------------------------------------
template<int EPI>
__global__ __launch_bounds__(256)
void gemm_bt(const ushort_t* __restrict__ A0, const ushort_t* __restrict__ A1,
             const ushort_t* __restrict__ A2, const ushort_t* __restrict__ Bt,
             const float* __restrict__ bias,
             float* __restrict__ C0, float* __restrict__ C1,
             float* __restrict__ C2,
             ushort_t* __restrict__ Cb0, ushort_t* __restrict__ Cb1,
             int M, int N, int K, int lda, int ldb,
             size_t strideB, int biasStride,
             const float* __restrict__ gates, int expertBase)
{
    __shared__ ushort_t Alds[128 * 32];
    __shared__ ushort_t Blds[128 * 32];

    const int tid = threadIdx.x;
    const int w  = tid >> 6, l = tid & 63;
    const int wr = w >> 1,  wc = w & 1;
    const int rg = l >> 4,  fr = l & 15;
    const int brow = blockIdx.y * 128;
    const int bcol = blockIdx.x * 128;
    const int z    = blockIdx.z;

    int e = 0, koff = 0;
    const ushort_t* A = A0;
    const ushort_t* Bp = Bt;
    if (EPI == 1) { e = z; Bp += (size_t)e * strideB; }
    if (EPI == 2) { e = z >> 1; koff = (z & 1) * K; A = e ? A1 : A0;
                    Bp += (size_t)e * strideB; }

    // QKV segment select (block-uniform: 768 % 128 == 0)
    const int seg = (EPI == 3) ? (bcol / 768) : 0;
    if (EPI == 3) A = (seg == 0 ? A0 : seg == 1 ? A1 : A2);
    float* Cf = (EPI == 3) ? (seg == 0 ? C0 : seg == 1 ? C1 : C2) : C0;
    const int ldc   = (EPI == 3) ? 768 : N;
    const int ccol0 = (EPI == 3) ? (bcol - seg * 768) : bcol;

    const int srow = tid >> 2;            // 0..63
    const int scol = (tid & 3) << 3;      // 0,8,16,24
    const ushort_t* gA = A  + (size_t)(brow + srow) * lda + koff + scol;
    const ushort_t* gB = Bp + (size_t)(bcol + srow) * ldb + koff + scol;
    ushort_t* lA = &Alds[w * 512];
    ushort_t* lB = &Blds[w * 512];

    f32x4 acc[4][4] = {};
    const int aoff = (wr * 64 + fr) * 32 + rg * 8;
    const int boff = (wc * 64 + fr) * 32 + rg * 8;

    for (int k0 = 0; k0 < K; k0 += 32) {
        if (k0) __syncthreads();
        glds16(gA,                    lA);
        glds16(gA + (size_t)64 * lda, lA + 2048);
        glds16(gB,                    lB);
        glds16(gB + (size_t)64 * ldb, lB + 2048);
        gA += 32; gB += 32;
        __syncthreads();

        ABFrag af[4], bfr[4];
        #pragma unroll
        for (int m = 0; m < 4; ++m) af[m]  = *(const ABFrag*)&Alds[aoff + m * 512];
        #pragma unroll
        for (int n = 0; n < 4; ++n) bfr[n] = *(const ABFrag*)&Blds[boff + n * 512];
        #pragma unroll
        for (int m = 0; m < 4; ++m)
            #pragma unroll
            for (int n = 0; n < 4; ++n)
                acc[m][n] = __builtin_amdgcn_mfma_f32_16x16x32_bf16(
                                af[m], bfr[n], acc[m][n], 0, 0, 0);
    }

    // D frag: col = lane&15, row = (lane>>4)*4 + reg
    #pragma unroll
    for (int m = 0; m < 4; ++m) {
        #pragma unroll
        for (int n = 0; n < 4; ++n) {
            const int cg   = bcol  + wc * 64 + n * 16 + fr;   // tile-global col
            const int ocol = ccol0 + wc * 64 + n * 16 + fr;   // output col
            float bv;
            if (EPI == 1)      bv = bias[e * biasStride + cg];
            else if (EPI == 2) bv = (z & 1) ? 0.f : bias[e * biasStride + cg];
            else               bv = bias[cg];
            #pragma unroll
            for (int j = 0; j < 4; ++j) {
                const int row = brow + wr * 64 + m * 16 + rg * 4 + j;
                float vv = acc[m][n][j] + bv;
                if (EPI == 1) {
                    vv = 0.5f * vv * (1.0f + erff(vv * 0.70710678118654752f));
                    (e ? Cb1 : Cb0)[(size_t)row * N + ocol] = f2bf(vv);
                } else if (EPI == 2) {
                    atomAddF(&Cf[(size_t)row * ldc + ocol],
                             gates[(size_t)row * E_ + expertBase + e] * vv);
                } else {
                    Cf[(size_t)row * ldc + ocol] = vv;
                }
            }
        }
    }
}

// ---------------------------------------------------------------------------
// fp32 -> bf16 linear convert (float4 per thread)
// ---------------------------------------------------------------------------
__global__ __launch_bounds__(256)
void convert_bf16(const float* __restrict__ in, ushort_t* __restrict__ out)
{
    const int i = blockIdx.x * 256 + threadIdx.x;
    float4 v = ((const float4*)in)[i];
    ushort4 o;
    o.x = f2bf(v.x); o.y = f2bf(v.y); o.z = f2bf(v.z); o.w = f2bf(v.w);
    ((ushort4*)out)[i] = o;
}

// ---------------------------------------------------------------------------
// fp32 [R][C] -> bf16 [C][R] transpose (R, C multiples of 64); z-batched.
// ---------------------------------------------------------------------------
__global__ __launch_bounds__(256)
void transpose_to_bf16(const float* __restrict__ in, ushort_t* __restrict__ out,
                       int R, int C, size_t inStride, size_t outStride)
{
    __shared__ float tile[64][65];
    in  += (size_t)blockIdx.z * inStride;
    out += (size_t)blockIdx.z * outStride;
    const int bc = blockIdx.x * 64;
    const int br = blockIdx.y * 64;
    const int lr = threadIdx.x >> 4;
    const int lc = (threadIdx.x & 15) << 2;
    #pragma unroll
    for (int i = 0; i < 64; i += 16) {
        float4 v = *(const float4*)&in[(size_t)(br + lr + i) * C + bc + lc];
        tile[lr + i][lc + 0] = v.x; tile[lr + i][lc + 1] = v.y;
        tile[lr + i][lc + 2] = v.z; tile[lr + i][lc + 3] = v.w;
    }
    __syncthreads();
    #pragma unroll
    for (int i = 0; i < 64; i += 16) {
        const int orow = lr + i;
        ushort4 o;
        o.x = f2bf(tile[lc + 0][orow]);
        o.y = f2bf(tile[lc + 1][orow]);
        o.z = f2bf(tile[lc + 2][orow]);
        o.w = f2bf(tile[lc + 3][orow]);
        *(ushort4*)&out[(size_t)(bc + orow) * R + br + lc] = o;
    }
}

// ---------------------------------------------------------------------------
// Attention, chunked online softmax (KB=28, 7 chunks of 196 exactly).
// One block per (b,h); K in LDS; per-thread q-row; V broadcast from global.
// One branch-free rescale per chunk instead of per key.
// ---------------------------------------------------------------------------
#define KB_ 28
__global__ __launch_bounds__(256)
void attn_kernel(const float* __restrict__ qh, const float* __restrict__ kh,
                 const float* __restrict__ vh, float* __restrict__ ctx)
{
    __shared__ float Ks[S_ * DH_];   // 50,176 B
    const int bh = blockIdx.x;
    const int b  = bh / H_;
    const int h  = bh % H_;
    const int tid = threadIdx.x;

    for (int i = tid; i < S_ * 16; i += 256) {           // S_*16 float4s
        const int s = i >> 4, d4 = i & 15;
        ((float4*)Ks)[s * 16 + d4] =
            *(const float4*)&kh[((size_t)(b * S_ + s)) * D_ + h * DH_ + d4 * 4];
    }
    __syncthreads();
    if (tid >= S_) return;

    float qf[DH_];
    const float* qrow = qh + ((size_t)(b * S_ + tid)) * D_ + h * DH_;
    #pragma unroll
    for (int d = 0; d < DH_; d += 4) {
        float4 v4 = *(const float4*)(qrow + d);
        qf[d+0] = v4.x * 0.125f; qf[d+1] = v4.y * 0.125f;   // fold 1/sqrt(64)
        qf[d+2] = v4.z * 0.125f; qf[d+3] = v4.w * 0.125f;
    }

    float m = -1e30f, lsum = 0.f;
    float acc[DH_] = {};
    const float* vbase = vh + ((size_t)b * S_) * D_ + h * DH_;

    for (int kc = 0; kc < S_; kc += KB_) {
        float sc[KB_];
        #pragma unroll
        for (int kk = 0; kk < KB_; ++kk) {
            const float* kr = &Ks[(kc + kk) * DH_];
            float s0 = 0.f, s1 = 0.f, s2 = 0.f, s3 = 0.f;
            #pragma unroll
            for (int d = 0; d < DH_; d += 4) {
                s0 = fmaf(qf[d+0], kr[d+0], s0);
                s1 = fmaf(qf[d+1], kr[d+1], s1);
                s2 = fmaf(qf[d+2], kr[d+2], s2);
                s3 = fmaf(qf[d+3], kr[d+3], s3);
            }
            sc[kk] = (s0 + s1) + (s2 + s3);
        }
        // chunk max (tree)
        float cmax = sc[0];
        #pragma unroll
        for (int kk = 1; kk < KB_; ++kk) cmax = fmaxf(cmax, sc[kk]);
        const float newm  = fmaxf(m, cmax);
        const float alpha = __expf(m - newm);   // exp(-inf)=0 on first chunk
        lsum *= alpha;
        #pragma unroll
        for (int d = 0; d < DH_; ++d) acc[d] *= alpha;
        m = newm;
        // exps (independent), then weighted V accumulate
        #pragma unroll
        for (int kk = 0; kk < KB_; ++kk) {
            sc[kk] = __expf(sc[kk] - m);
            lsum  += sc[kk];
        }
        #pragma unroll
        for (int kk = 0; kk < KB_; ++kk) {
            const float p = sc[kk];
            const float* vr = vbase + (size_t)(kc + kk) * D_;
            #pragma unroll
            for (int d = 0; d < DH_; d += 4) {
                float4 v4 = *(const float4*)(vr + d);
                acc[d+0] = fmaf(p, v4.x, acc[d+0]);
                acc[d+1] = fmaf(p, v4.y, acc[d+1]);
                acc[d+2] = fmaf(p, v4.z, acc[d+2]);
                acc[d+3] = fmaf(p, v4.w, acc[d+3]);
            }
        }
    }
    const float inv = 1.f / lsum;
    float* crow = ctx + ((size_t)(b * S_ + tid)) * D_ + h * DH_;
    #pragma unroll
    for (int d = 0; d < DH_; ++d) crow[d] = acc[d] * inv;
}

// ---------------------------------------------------------------------------
// Residual + LayerNorm (+ optional zero of another buffer's same row)
// ---------------------------------------------------------------------------
__device__ __forceinline__ float block_sum(float v, float* red)
{
    __syncthreads();
    const int lane = threadIdx.x & 63;
    const int wid  = threadIdx.x >> 6;
    #pragma unroll
    for (int off = 32; off > 0; off >>= 1) v += __shfl_down(v, off);
    if (lane == 0) red[wid] = v;
    __syncthreads();
    return red[0] + red[1] + red[2] + red[3];
}

__global__ __launch_bounds__(256)
void ln_kernel(const float* __restrict__ a, const float* __restrict__ bres,
               const float* __restrict__ g, const float* __restrict__ beta,
               float* __restrict__ out, float* __restrict__ zt)
{
    __shared__ float red[4];
    const int t   = blockIdx.x;
    const int tid = threadIdx.x;
    const float* ar = a    + (size_t)t * D_;
    const float* br = bres + (size_t)t * D_;

    float vals[3];
    float s = 0.f;
    #pragma unroll
    for (int i = 0; i < 3; ++i) {
        const int d = tid + i * 256;
        const float x = ar[d] + br[d];
        vals[i] = x;
        s += x;
        if (zt) zt[(size_t)t * D_ + d] = 0.f;
    }
    s = block_sum(s, red);
    const float mu = s * (1.f / D_);
    float qv = 0.f;
    #pragma unroll
    for (int i = 0; i < 3; ++i) { const float dv = vals[i] - mu; qv += dv * dv; }
    qv = block_sum(qv, red);
    const float rstd = rsqrtf(qv * (1.f / D_) + 1e-5f);
    #pragma unroll
    for (int i = 0; i < 3; ++i) {
        const int d = tid + i * 256;
        out[(size_t)t * D_ + d] = (vals[i] - mu) * rstd * g[d] + beta[d];
    }
}

// ---------------------------------------------------------------------------
// Gate: gates = softmax(x @ Wg + bg). One wave per token.
// ---------------------------------------------------------------------------
__global__ __launch_bounds__(256)
void gate_kernel(const float* __restrict__ x, const float* __restrict__ Wg,
                 const float* __restrict__ bg, float* __restrict__ gates)
{
    const int lane = threadIdx.x & 63;
    const int wid  = threadIdx.x >> 6;
    const int t = blockIdx.x * 4 + wid;
    const float* xr = x + (size_t)t * D_;

    float accv[E_];
    #pragma unroll
    for (int e = 0; e < E_; ++e) accv[e] = 0.f;
    for (int d = lane; d < D_; d += 64) {
        const float xv = xr[d];
        const float* wr = Wg + (size_t)d * E_;
        #pragma unroll
        for (int e = 0; e < E_; ++e) accv[e] = fmaf(xv, wr[e], accv[e]);
    }
    #pragma unroll
    for (int e = 0; e < E_; ++e) {
        #pragma unroll
        for (int off = 32; off > 0; off >>= 1)
            accv[e] += __shfl_down(accv[e], off);
    }
    if (lane == 0) {
        float mx = -1e30f;
        #pragma unroll
        for (int e = 0; e < E_; ++e) { accv[e] += bg[e]; mx = fmaxf(mx, accv[e]); }
        float lsum = 0.f;
        #pragma unroll
        for (int e = 0; e < E_; ++e) { const float p = expf(accv[e] - mx); accv[e] = p; lsum += p; }
        const float inv = 1.f / lsum;
        #pragma unroll
        for (int e = 0; e < E_; ++e) gates[(size_t)t * E_ + e] = accv[e] * inv;
    }
}

__global__ void concat3_kernel(const float* __restrict__ a, const float* __restrict__ b,
                               const float* __restrict__ c, float* __restrict__ o)
{
    const int i = blockIdx.x * 256 + threadIdx.x;
    if (i < 768)       o[i] = a[i];
    else if (i < 1536) o[i] = b[i - 768];
    else if (i < 2304) o[i] = c[i - 1536];
}

// ---------------------------------------------------------------------------
// Orchestration. Workspace (float offsets), peak ~158 MB:
//   [0,TD)     qh -> attnout -> {xb (bf16), gates (+TD/2)}
//   [TD,2TD)   kh -> x (live to end)
//   [2TD,4TD)  vh, ctx -> h0 (T*F bf16)
//   [4TD,5TD)  moe accumulator
//   [5TD,7TD)  qb,kb,vb (bf16; 1.5TD) + ctxb -> h1 (T*F bf16 = 2TD)
//   [7TD,...)  wqkvt(3DD u) wot(DD u) bcat(2304 f) w1t_g(2DF u) w2t_g(2DF u)
// ---------------------------------------------------------------------------
extern "C" void kernel_launch(void* const* d_in, const int* in_sizes, int n_in,
                              void* d_out, int out_size, void* d_ws, size_t ws_size,
                              hipStream_t stream)
{
    const float* q    = (const float*)d_in[0];
    const float* k    = (const float*)d_in[1];
    const float* v    = (const float*)d_in[2];
    const float* Wq   = (const float*)d_in[3];
    const float* bq   = (const float*)d_in[4];
    const float* Wk   = (const float*)d_in[5];
    const float* bk   = (const float*)d_in[6];
    const float* Wv   = (const float*)d_in[7];
    const float* bv   = (const float*)d_in[8];
    const float* Wo   = (const float*)d_in[9];
    const float* bo   = (const float*)d_in[10];
    const float* ln1g = (const float*)d_in[11];
    const float* ln1b = (const float*)d_in[12];
    const float* ln2g = (const float*)d_in[13];
    const float* ln2b = (const float*)d_in[14];
    const float* Wg   = (const float*)d_in[15];
    const float* bg   = (const float*)d_in[16];
    const float* W1   = (const float*)d_in[17];
    const float* b1   = (const float*)d_in[18];
    const float* W2   = (const float*)d_in[19];
    const float* b2   = (const float*)d_in[20];
    float* out = (float*)d_out;
    float* ws  = (float*)d_ws;

    const size_t TD = (size_t)T_ * D_;                 // 4,816,896
    const size_t DD = (size_t)D_ * D_;                 // 589,824
    const size_t DF = (size_t)D_ * F_;                 // 2,359,296

    float* qh      = ws;                               // -> attnout
    float* x       = ws + TD;                          // kh -> x
    float* kh      = x;
    float* vh      = ws + 2 * TD;
    float* ctx     = ws + 3 * TD;
    float* moe     = ws + 4 * TD;
    ushort_t* hb0  = (ushort_t*)(ws + 2 * TD);         // T*F bf16 over vh+ctx
    ushort_t* hb1  = (ushort_t*)(ws + 5 * TD);         // T*F bf16 over qb..
    ushort_t* xb   = (ushort_t*)qh;                    // after attnout dead
    float* gates   = qh + TD / 2;
    float* attnout = qh;

    ushort_t* qb   = (ushort_t*)(ws + 5 * TD);
    ushort_t* kb   = qb + TD;
    ushort_t* vb   = kb + TD;
    ushort_t* ctxb = qb;                               // qb dead after QKV

    ushort_t* wqkvt = (ushort_t*)(ws + 7 * TD);
    ushort_t* wot   = wqkvt + 3 * DD;
    float*    bcat  = (float*)(wot + DD);
    ushort_t* w1t   = (ushort_t*)(bcat + 2304);        // 2 experts
    ushort_t* w2t   = w1t + 2 * DF;                    // 2 experts

    const dim3 blk(256);
    const int  cgrid = (int)(TD / 1024);               // convert grid (exact)

    // --- Phase 0: weight prep ---
    concat3_kernel<<<dim3(9), blk, 0, stream>>>(bq, bk, bv, bcat);
    transpose_to_bf16<<<dim3(D_/64, D_/64), blk, 0, stream>>>(Wq, wqkvt,          D_, D_, 0, 0);
    transpose_to_bf16<<<dim3(D_/64, D_/64), blk, 0, stream>>>(Wk, wqkvt + DD,     D_, D_, 0, 0);
    transpose_to_bf16<<<dim3(D_/64, D_/64), blk, 0, stream>>>(Wv, wqkvt + 2 * DD, D_, D_, 0, 0);
    transpose_to_bf16<<<dim3(D_/64, D_/64), blk, 0, stream>>>(Wo, wot,            D_, D_, 0, 0);

    // --- Phase 1: inputs -> bf16, fused QKV GEMM ---
    convert_bf16<<<cgrid, blk, 0, stream>>>(q, qb);
    convert_bf16<<<cgrid, blk, 0, stream>>>(k, kb);
    convert_bf16<<<cgrid, blk, 0, stream>>>(v, vb);
    gemm_bt<3><<<dim3(18, 49), blk, 0, stream>>>(qb, kb, vb, wqkvt, bcat,
                                                 qh, kh, vh, nullptr, nullptr,
                                                 T_, 2304, D_, D_, D_, 0, 0,
                                                 nullptr, 0);

    // --- Phase 2: attention (no scratch) ---
    attn_kernel<<<dim3(B_ * H_), blk, 0, stream>>>(qh, kh, vh, ctx);

    // --- Phase 3: Wo projection, residual + LN1 (+ zero moe) ---
    convert_bf16<<<cgrid, blk, 0, stream>>>(ctx, ctxb);
    gemm_bt<0><<<dim3(6, 49), blk, 0, stream>>>(ctxb, nullptr, nullptr, wot, bo,
                                                attnout, nullptr, nullptr, nullptr, nullptr,
                                                T_, D_, D_, D_, D_, 0, 0, nullptr, 0);
    ln_kernel<<<dim3(T_), blk, 0, stream>>>(q, attnout, ln1g, ln1b, x, moe);

    // --- Phase 4: gating, x -> bf16 ---
    gate_kernel<<<dim3(T_ / 4), blk, 0, stream>>>(x, Wg, bg, gates);
    convert_bf16<<<cgrid, blk, 0, stream>>>(x, xb);

    // --- Phase 5: MoE, expert pairs (z-batched; W2 split-K2 + atomics) ---
    for (int g = 0; g < 4; ++g) {
        const int e0 = 2 * g;
        transpose_to_bf16<<<dim3(F_/64, D_/64, 2), blk, 0, stream>>>(
            W1 + (size_t)e0 * DF, w1t, D_, F_, DF, DF);
        transpose_to_bf16<<<dim3(D_/64, F_/64, 2), blk, 0, stream>>>(
            W2 + (size_t)e0 * DF, w2t, F_, D_, DF, DF);
        // h_e = GELU(x @ W1_e + b1_e), e in {e0, e0+1}
        gemm_bt<1><<<dim3(24, 49, 2), blk, 0, stream>>>(
            xb, nullptr, nullptr, w1t, b1 + (size_t)e0 * F_,
            nullptr, nullptr, nullptr, hb0, hb1,
            T_, F_, D_, D_, D_, DF, F_, nullptr, 0);
        // moe += gate_e * (h_e @ W2_e + b2_e), split-K x2
        gemm_bt<2><<<dim3(6, 49, 4), blk, 0, stream>>>(
            hb0, hb1, nullptr, w2t, b2 + (size_t)e0 * D_,
            moe, nullptr, nullptr, nullptr, nullptr,
            T_, D_, F_ / 2, F_, F_, DF, D_, gates, e0);
    }

    // --- Phase 6: residual + LN2 -> output ---
    ln_kernel<<<dim3(T_), blk, 0, stream>>>(x, moe, ln2g, ln2b, out, nullptr);
}

// Round 7
// 1452.412 us; speedup vs baseline: 1.3080x; 1.1231x over previous
//
#include <hip/hip_runtime.h>
#include <cmath>

// Problem constants (fixed by the reference)
#define B_  32
#define S_  196
#define D_  768
#define H_  12
#define E_  8
#define F_  3072
#define DH_ 64
#define T_  (B_ * S_)   // 6272 tokens; 6272 % 128 == 0
#define PR_ (B_ * H_ * S_)   // 75264 partial rows per K-split

typedef unsigned short ushort_t;
typedef short   s16x8   __attribute__((ext_vector_type(8)));
typedef __bf16  bf16x8_t __attribute__((ext_vector_type(8)));
typedef float   f32x4   __attribute__((ext_vector_type(4)));

// 16-byte MFMA A/B fragment; converts to whichever vector type the builtin wants.
struct ABFrag {
    unsigned int r[4];
    __device__ operator s16x8()    const { return __builtin_bit_cast(s16x8, *this); }
    __device__ operator bf16x8_t() const { return __builtin_bit_cast(bf16x8_t, *this); }
};

__device__ __forceinline__ ushort_t f2bf(float f) {
    unsigned int x = __float_as_uint(f);
    return (ushort_t)((x + 0x7fffu + ((x >> 16) & 1u)) >> 16);   // RNE
}

// async global->LDS, 16B per lane (dest wave-uniform base, HW adds lane*16)
__device__ __forceinline__ void glds16(const void* g, void* l) {
    __builtin_amdgcn_global_load_lds((const __attribute__((address_space(1))) void*)g,
                                     (__attribute__((address_space(3))) void*)l,
                                     16, 0, 0);
}

// native fp32 atomic add (agent scope -> global_atomic_add_f32, no CAS loop)
__device__ __forceinline__ void atomAddF(float* p, float v) {
    __hip_atomic_fetch_add(p, v, __ATOMIC_RELAXED, __HIP_MEMORY_SCOPE_AGENT);
}

// cheap exact-enough GELU: tanh form with tanh via HW exp (err <= ~1e-3 abs)
__device__ __forceinline__ float gelu_f(float x) {
    const float y = 0.7978845608028654f * (x + 0.044715f * x * x * x);
    const float t = __expf(fminf(2.f * y, 80.f));
    return 0.5f * x * (1.f + (t - 1.f) / (t + 1.f));
}

// ---------------------------------------------------------------------------
// bf16 MFMA GEMM: C = A @ Bt^T.  128x128 tile, BK=64, 256 threads (4 waves
// 2x2), wave = 64x64 = 4x4 16x16x32 frags x 2 k-slices.
// LDS [row][k] linear with k-chunk XOR swizzle: LDS slot (row, c8) holds
// global k-chunk (c8 ^ (row&7)); staged by pre-swizzling the GLOBAL source
// column (dest of global_load_lds must stay linear), read back with the
// same XOR -> 2-way bank conflict (free) instead of 16-way.
// EPI 0: fp32 out + bias                       (z unused)
// EPI 1: batched W1: e=z; B+=e*strideB; bf16 out (e? Cb1:Cb0) = GELU(acc+bias)
// EPI 2: batched W2 split-K2: e=z>>1, kchunk=z&1; A=(e?A1:A0); B+=e*strideB;
//        koff=kchunk*K; atomic C0 += gates[row,eb+e]*(acc + (kchunk==0)*bias)
// EPI 3: fused QKV: col segment s=bcol/768 selects A{0,1,2}, C{0,1,2}
// ---------------------------------------------------------------------------
template<int EPI>
__global__ __launch_bounds__(256)
void gemm_bt(const ushort_t* __restrict__ A0, const ushort_t* __restrict__ A1,
             const ushort_t* __restrict__ A2, const ushort_t* __restrict__ Bt,
             const float* __restrict__ bias,
             float* __restrict__ C0, float* __restrict__ C1,
             float* __restrict__ C2,
             ushort_t* __restrict__ Cb0, ushort_t* __restrict__ Cb1,
             int M, int N, int K, int lda, int ldb,
             size_t strideB, int biasStride,
             const float* __restrict__ gates, int expertBase)
{
    __shared__ ushort_t Alds[128 * 64];   // 16 KB
    __shared__ ushort_t Blds[128 * 64];   // 16 KB

    const int tid = threadIdx.x;
    const int w  = tid >> 6, l = tid & 63;
    const int wr = w >> 1,  wc = w & 1;
    const int rg = l >> 4,  fr = l & 15;
    const int brow = blockIdx.y * 128;
    const int bcol = blockIdx.x * 128;
    const int z    = blockIdx.z;

    int e = 0, koff = 0;
    const ushort_t* A = A0;
    const ushort_t* Bp = Bt;
    if (EPI == 1) { e = z; Bp += (size_t)e * strideB; }
    if (EPI == 2) { e = z >> 1; koff = (z & 1) * K; A = e ? A1 : A0;
                    Bp += (size_t)e * strideB; }

    // QKV segment select (block-uniform: 768 % 128 == 0)
    const int seg = (EPI == 3) ? (bcol / 768) : 0;
    if (EPI == 3) A = (seg == 0 ? A0 : seg == 1 ? A1 : A2);
    float* Cf = (EPI == 3) ? (seg == 0 ? C0 : seg == 1 ? C1 : C2) : C0;
    const int ldc   = (EPI == 3) ? 768 : N;
    const int ccol0 = (EPI == 3) ? (bcol - seg * 768) : bcol;

    // staging: thread t, sweep s covers LDS elems t*8 + s*2048
    //   (row = (tid>>3) + s*32, k-slot = (tid&7)*8); global col pre-swizzled
    const int srow = tid >> 3;                       // 0..31
    const int scol = ((tid & 7) << 3) ^ ((srow & 7) << 3);
    const ushort_t* gA = A  + (size_t)(brow + srow) * lda + koff + scol;
    const ushort_t* gB = Bp + (size_t)(bcol + srow) * ldb + koff + scol;
    ushort_t* lA = &Alds[w * 512];                   // + s*2048 per sweep
    ushort_t* lB = &Blds[w * 512];

    f32x4 acc[4][4] = {};
    const int arow0 = (wr * 64 + fr) * 64;
    const int brow0 = (wc * 64 + fr) * 64;

    for (int k0 = 0; k0 < K; k0 += 64) {
        if (k0) __syncthreads();
        #pragma unroll
        for (int s = 0; s < 4; ++s) {
            glds16(gA + (size_t)(s * 32) * lda, lA + s * 2048);
            glds16(gB + (size_t)(s * 32) * ldb, lB + s * 2048);
        }
        gA += 64; gB += 64;
        __syncthreads();

        #pragma unroll
        for (int kk = 0; kk < 2; ++kk) {
            const int xk = (((kk << 2) | rg) ^ (fr & 7)) << 3;  // swizzled k off
            ABFrag af[4], bfr[4];
            #pragma unroll
            for (int m = 0; m < 4; ++m)
                af[m]  = *(const ABFrag*)&Alds[arow0 + m * 1024 + xk];
            #pragma unroll
            for (int n = 0; n < 4; ++n)
                bfr[n] = *(const ABFrag*)&Blds[brow0 + n * 1024 + xk];
            #pragma unroll
            for (int m = 0; m < 4; ++m)
                #pragma unroll
                for (int n = 0; n < 4; ++n)
                    acc[m][n] = __builtin_amdgcn_mfma_f32_16x16x32_bf16(
                                    af[m], bfr[n], acc[m][n], 0, 0, 0);
        }
    }

    // D frag: col = lane&15, row = (lane>>4)*4 + reg
    #pragma unroll
    for (int m = 0; m < 4; ++m) {
        #pragma unroll
        for (int n = 0; n < 4; ++n) {
            const int cg   = bcol  + wc * 64 + n * 16 + fr;   // tile-global col
            const int ocol = ccol0 + wc * 64 + n * 16 + fr;   // output col
            float bv;
            if (EPI == 1)      bv = bias[e * biasStride + cg];
            else if (EPI == 2) bv = (z & 1) ? 0.f : bias[e * biasStride + cg];
            else               bv = bias[cg];
            #pragma unroll
            for (int j = 0; j < 4; ++j) {
                const int row = brow + wr * 64 + m * 16 + rg * 4 + j;
                float vv = acc[m][n][j] + bv;
                if (EPI == 1) {
                    vv = gelu_f(vv);
                    (e ? Cb1 : Cb0)[(size_t)row * N + ocol] = f2bf(vv);
                } else if (EPI == 2) {
                    atomAddF(&Cf[(size_t)row * ldc + ocol],
                             gates[(size_t)row * E_ + expertBase + e] * vv);
                } else {
                    Cf[(size_t)row * ldc + ocol] = vv;
                }
            }
        }
    }
}

// ---------------------------------------------------------------------------
// fp32 -> bf16 linear convert (float4 per thread)
// ---------------------------------------------------------------------------
__global__ __launch_bounds__(256)
void convert_bf16(const float* __restrict__ in, ushort_t* __restrict__ out)
{
    const int i = blockIdx.x * 256 + threadIdx.x;
    float4 v = ((const float4*)in)[i];
    ushort4 o;
    o.x = f2bf(v.x); o.y = f2bf(v.y); o.z = f2bf(v.z); o.w = f2bf(v.w);
    ((ushort4*)out)[i] = o;
}

// ---------------------------------------------------------------------------
// fp32 [R][C] -> bf16 [C][R] transpose (R, C multiples of 64); z-batched.
// ---------------------------------------------------------------------------
__global__ __launch_bounds__(256)
void transpose_to_bf16(const float* __restrict__ in, ushort_t* __restrict__ out,
                       int R, int C, size_t inStride, size_t outStride)
{
    __shared__ float tile[64][65];
    in  += (size_t)blockIdx.z * inStride;
    out += (size_t)blockIdx.z * outStride;
    const int bc = blockIdx.x * 64;
    const int br = blockIdx.y * 64;
    const int lr = threadIdx.x >> 4;
    const int lc = (threadIdx.x & 15) << 2;
    #pragma unroll
    for (int i = 0; i < 64; i += 16) {
        float4 v = *(const float4*)&in[(size_t)(br + lr + i) * C + bc + lc];
        tile[lr + i][lc + 0] = v.x; tile[lr + i][lc + 1] = v.y;
        tile[lr + i][lc + 2] = v.z; tile[lr + i][lc + 3] = v.w;
    }
    __syncthreads();
    #pragma unroll
    for (int i = 0; i < 64; i += 16) {
        const int orow = lr + i;
        ushort4 o;
        o.x = f2bf(tile[lc + 0][orow]);
        o.y = f2bf(tile[lc + 1][orow]);
        o.z = f2bf(tile[lc + 2][orow]);
        o.w = f2bf(tile[lc + 3][orow]);
        *(ushort4*)&out[(size_t)(bc + orow) * R + br + lc] = o;
    }
}

// ---------------------------------------------------------------------------
// Attention stage 1: split-K flash partials. Block = (b, h, kc); kc in {0,1}
// covers keys [kc*98, kc*98+98). K-half in LDS; per-thread q-row online
// softmax over 7 chunks of 14. Writes unnormalized acc + (m, l).
// Grid 768 blocks = 3 blocks/CU fully resident.
// ---------------------------------------------------------------------------
#define KL_  (S_ / 2)   // 98
#define KB2_ 14         // 7 chunks
__global__ __launch_bounds__(256)
void attn_part(const float* __restrict__ qh, const float* __restrict__ kh,
               const float* __restrict__ vh, float* __restrict__ part,
               float* __restrict__ ml)
{
    __shared__ float Ks[KL_ * DH_];   // 25,088 B
    const int blk = blockIdx.x;
    const int bh  = blk >> 1;
    const int kc  = blk & 1;
    const int b = bh / H_, h = bh % H_;
    const int tid = threadIdx.x;
    const int k0 = kc * KL_;

    for (int i = tid; i < KL_ * 16; i += 256) {          // KL_*16 float4s
        const int s = i >> 4, d4 = i & 15;
        ((float4*)Ks)[i] =
            *(const float4*)&kh[((size_t)(b * S_ + k0 + s)) * D_ + h * DH_ + d4 * 4];
    }
    __syncthreads();
    if (tid >= S_) return;

    float qf[DH_];
    const float* qrow = qh + ((size_t)(b * S_ + tid)) * D_ + h * DH_;
    #pragma unroll
    for (int d = 0; d < DH_; d += 4) {
        float4 v4 = *(const float4*)(qrow + d);
        qf[d+0] = v4.x * 0.125f; qf[d+1] = v4.y * 0.125f;   // fold 1/sqrt(64)
        qf[d+2] = v4.z * 0.125f; qf[d+3] = v4.w * 0.125f;
    }

    float m = -1e30f, lsum = 0.f;
    float acc[DH_] = {};
    const float* vbase = vh + ((size_t)(b * S_ + k0)) * D_ + h * DH_;

    for (int kch = 0; kch < KL_; kch += KB2_) {
        float sc[KB2_];
        #pragma unroll
        for (int kk = 0; kk < KB2_; ++kk) {
            const float* kr = &Ks[(kch + kk) * DH_];
            float s0 = 0.f, s1 = 0.f, s2 = 0.f, s3 = 0.f;
            #pragma unroll
            for (int d = 0; d < DH_; d += 4) {
                s0 = fmaf(qf[d+0], kr[d+0], s0);
                s1 = fmaf(qf[d+1], kr[d+1], s1);
                s2 = fmaf(qf[d+2], kr[d+2], s2);
                s3 = fmaf(qf[d+3], kr[d+3], s3);
            }
            sc[kk] = (s0 + s1) + (s2 + s3);
        }
        float cmax = sc[0];
        #pragma unroll
        for (int kk = 1; kk < KB2_; ++kk) cmax = fmaxf(cmax, sc[kk]);
        const float newm  = fmaxf(m, cmax);
        const float alpha = __expf(m - newm);
        lsum *= alpha;
        #pragma unroll
        for (int d = 0; d < DH_; ++d) acc[d] *= alpha;
        m = newm;
        #pragma unroll
        for (int kk = 0; kk < KB2_; ++kk) {
            sc[kk] = __expf(sc[kk] - m);
            lsum  += sc[kk];
        }
        #pragma unroll
        for (int kk = 0; kk < KB2_; ++kk) {
            const float p = sc[kk];
            const float* vr = vbase + (size_t)(kch + kk) * D_;
            #pragma unroll
            for (int d = 0; d < DH_; d += 4) {
                float4 v4 = *(const float4*)(vr + d);
                acc[d+0] = fmaf(p, v4.x, acc[d+0]);
                acc[d+1] = fmaf(p, v4.y, acc[d+1]);
                acc[d+2] = fmaf(p, v4.z, acc[d+2]);
                acc[d+3] = fmaf(p, v4.w, acc[d+3]);
            }
        }
    }

    const size_t r = (size_t)kc * PR_ + (size_t)bh * S_ + tid;
    float* pr = part + r * DH_;
    #pragma unroll
    for (int d = 0; d < DH_; d += 4)
        *(float4*)(pr + d) = make_float4(acc[d], acc[d+1], acc[d+2], acc[d+3]);
    ((float2*)ml)[r] = make_float2(m, lsum);
}

// ---------------------------------------------------------------------------
// Attention stage 2: merge the 2 partials, normalize, emit ctx as bf16.
// One thread per output element (PR_*64 total, exact grid).
// ---------------------------------------------------------------------------
__global__ __launch_bounds__(256)
void attn_combine(const float* __restrict__ part, const float* __restrict__ ml,
                  ushort_t* __restrict__ ctxb)
{
    const size_t i   = (size_t)blockIdx.x * 256 + threadIdx.x;
    const size_t row = i >> 6;            // bh*S + q
    const int d = (int)(i & 63);
    float2 ml0 = ((const float2*)ml)[row];
    float2 ml1 = ((const float2*)ml)[PR_ + row];
    const float M  = fmaxf(ml0.x, ml1.x);
    const float e0 = __expf(ml0.x - M), e1 = __expf(ml1.x - M);
    const float inv = 1.f / (e0 * ml0.y + e1 * ml1.y);
    const float o = (e0 * part[row * 64 + d] +
                     e1 * part[(size_t)PR_ * 64 + row * 64 + d]) * inv;
    const int bh = (int)(row / S_), qi = (int)(row % S_);
    const int b = bh / H_, h = bh % H_;
    ctxb[((size_t)(b * S_ + qi)) * D_ + h * DH_ + d] = f2bf(o);
}

// ---------------------------------------------------------------------------
// Residual + LayerNorm; optionally emits bf16 copy of out and zeroes zt.
// ---------------------------------------------------------------------------
__device__ __forceinline__ float block_sum(float v, float* red)
{
    __syncthreads();
    const int lane = threadIdx.x & 63;
    const int wid  = threadIdx.x >> 6;
    #pragma unroll
    for (int off = 32; off > 0; off >>= 1) v += __shfl_down(v, off);
    if (lane == 0) red[wid] = v;
    __syncthreads();
    return red[0] + red[1] + red[2] + red[3];
}

__global__ __launch_bounds__(256)
void ln_kernel(const float* __restrict__ a, const float* __restrict__ bres,
               const float* __restrict__ g, const float* __restrict__ beta,
               float* __restrict__ out, ushort_t* __restrict__ xbout,
               float* __restrict__ zt)
{
    __shared__ float red[4];
    const int t   = blockIdx.x;
    const int tid = threadIdx.x;
    const float* ar = a    + (size_t)t * D_;
    const float* br = bres + (size_t)t * D_;

    float vals[3];
    float s = 0.f;
    #pragma unroll
    for (int i = 0; i < 3; ++i) {
        const int d = tid + i * 256;
        const float x = ar[d] + br[d];
        vals[i] = x;
        s += x;
        if (zt) zt[(size_t)t * D_ + d] = 0.f;
    }
    s = block_sum(s, red);
    const float mu = s * (1.f / D_);
    float qv = 0.f;
    #pragma unroll
    for (int i = 0; i < 3; ++i) { const float dv = vals[i] - mu; qv += dv * dv; }
    qv = block_sum(qv, red);
    const float rstd = rsqrtf(qv * (1.f / D_) + 1e-5f);
    #pragma unroll
    for (int i = 0; i < 3; ++i) {
        const int d = tid + i * 256;
        const float o = (vals[i] - mu) * rstd * g[d] + beta[d];
        out[(size_t)t * D_ + d] = o;
        if (xbout) xbout[(size_t)t * D_ + d] = f2bf(o);
    }
}

// ---------------------------------------------------------------------------
// Gate: gates = softmax(x @ Wg + bg). One wave per token.
// ---------------------------------------------------------------------------
__global__ __launch_bounds__(256)
void gate_kernel(const float* __restrict__ x, const float* __restrict__ Wg,
                 const float* __restrict__ bg, float* __restrict__ gates)
{
    const int lane = threadIdx.x & 63;
    const int wid  = threadIdx.x >> 6;
    const int t = blockIdx.x * 4 + wid;
    const float* xr = x + (size_t)t * D_;

    float accv[E_];
    #pragma unroll
    for (int e = 0; e < E_; ++e) accv[e] = 0.f;
    for (int d = lane; d < D_; d += 64) {
        const float xv = xr[d];
        const float* wr = Wg + (size_t)d * E_;
        #pragma unroll
        for (int e = 0; e < E_; ++e) accv[e] = fmaf(xv, wr[e], accv[e]);
    }
    #pragma unroll
    for (int e = 0; e < E_; ++e) {
        #pragma unroll
        for (int off = 32; off > 0; off >>= 1)
            accv[e] += __shfl_down(accv[e], off);
    }
    if (lane == 0) {
        float mx = -1e30f;
        #pragma unroll
        for (int e = 0; e < E_; ++e) { accv[e] += bg[e]; mx = fmaxf(mx, accv[e]); }
        float lsum = 0.f;
        #pragma unroll
        for (int e = 0; e < E_; ++e) { const float p = expf(accv[e] - mx); accv[e] = p; lsum += p; }
        const float inv = 1.f / lsum;
        #pragma unroll
        for (int e = 0; e < E_; ++e) gates[(size_t)t * E_ + e] = accv[e] * inv;
    }
}

__global__ void concat3_kernel(const float* __restrict__ a, const float* __restrict__ b,
                               const float* __restrict__ c, float* __restrict__ o)
{
    const int i = blockIdx.x * 256 + threadIdx.x;
    if (i < 768)       o[i] = a[i];
    else if (i < 1536) o[i] = b[i - 768];
    else if (i < 2304) o[i] = c[i - 1536];
}

// ---------------------------------------------------------------------------
// Orchestration. Workspace (float offsets), peak ~168 MB:
//   [0,TD)      qh -> attnout -> gates (+TD/2)
//   [TD,2TD)    kh -> x (live to end)
//   [2TD,3TD)   vh            -> hb0 low half
//   [3TD,4TD)   ctxb (bf16)   -> hb0 high half (hb0 = [2TD,4TD) bf16)
//   [4TD,5TD)   ml (attn) -> moe accumulator (zeroed by ln1)
//   [5TD,7TD)   qb,kb,vb (QKV inputs) -> part (attn) -> hb1 (bf16)
//   [7TD,...)   wqkvt | wot | bcat | w1t(2DF) | w2t(2DF) | xb (TD u)
// ---------------------------------------------------------------------------
extern "C" void kernel_launch(void* const* d_in, const int* in_sizes, int n_in,
                              void* d_out, int out_size, void* d_ws, size_t ws_size,
                              hipStream_t stream)
{
    const float* q    = (const float*)d_in[0];
    const float* k    = (const float*)d_in[1];
    const float* v    = (const float*)d_in[2];
    const float* Wq   = (const float*)d_in[3];
    const float* bq   = (const float*)d_in[4];
    const float* Wk   = (const float*)d_in[5];
    const float* bk   = (const float*)d_in[6];
    const float* Wv   = (const float*)d_in[7];
    const float* bv   = (const float*)d_in[8];
    const float* Wo   = (const float*)d_in[9];
    const float* bo   = (const float*)d_in[10];
    const float* ln1g = (const float*)d_in[11];
    const float* ln1b = (const float*)d_in[12];
    const float* ln2g = (const float*)d_in[13];
    const float* ln2b = (const float*)d_in[14];
    const float* Wg   = (const float*)d_in[15];
    const float* bg   = (const float*)d_in[16];
    const float* W1   = (const float*)d_in[17];
    const float* b1   = (const float*)d_in[18];
    const float* W2   = (const float*)d_in[19];
    const float* b2   = (const float*)d_in[20];
    float* out = (float*)d_out;
    float* ws  = (float*)d_ws;

    const size_t TD = (size_t)T_ * D_;                 // 4,816,896
    const size_t DD = (size_t)D_ * D_;                 // 589,824
    const size_t DF = (size_t)D_ * F_;                 // 2,359,296

    float* qh      = ws;                               // -> attnout
    float* x       = ws + TD;                          // kh -> x
    float* kh      = x;
    float* vh      = ws + 2 * TD;
    ushort_t* ctxb = (ushort_t*)(ws + 3 * TD);
    float* ml      = ws + 4 * TD;                      // -> moe
    float* moe     = ws + 4 * TD;
    float* part    = ws + 5 * TD;                      // 2TD floats
    ushort_t* hb0  = (ushort_t*)(ws + 2 * TD);         // T*F bf16
    ushort_t* hb1  = (ushort_t*)(ws + 5 * TD);         // T*F bf16
    float* gates   = qh + TD / 2;
    float* attnout = qh;

    ushort_t* qb   = (ushort_t*)(ws + 5 * TD);
    ushort_t* kb   = qb + TD;
    ushort_t* vb   = kb + TD;

    ushort_t* wqkvt = (ushort_t*)(ws + 7 * TD);
    ushort_t* wot   = wqkvt + 3 * DD;
    float*    bcat  = (float*)(wot + DD);
    ushort_t* w1t   = (ushort_t*)(bcat + 2304);        // 2 experts
    ushort_t* w2t   = w1t + 2 * DF;                    // 2 experts
    ushort_t* xb    = w2t + 2 * DF;                    // T*D bf16

    const dim3 blk(256);
    const int  cgrid = (int)(TD / 1024);               // convert grid (exact)

    // --- Phase 0: weight prep ---
    concat3_kernel<<<dim3(9), blk, 0, stream>>>(bq, bk, bv, bcat);
    transpose_to_bf16<<<dim3(D_/64, D_/64), blk, 0, stream>>>(Wq, wqkvt,          D_, D_, 0, 0);
    transpose_to_bf16<<<dim3(D_/64, D_/64), blk, 0, stream>>>(Wk, wqkvt + DD,     D_, D_, 0, 0);
    transpose_to_bf16<<<dim3(D_/64, D_/64), blk, 0, stream>>>(Wv, wqkvt + 2 * DD, D_, D_, 0, 0);
    transpose_to_bf16<<<dim3(D_/64, D_/64), blk, 0, stream>>>(Wo, wot,            D_, D_, 0, 0);

    // --- Phase 1: inputs -> bf16, fused QKV GEMM ---
    convert_bf16<<<cgrid, blk, 0, stream>>>(q, qb);
    convert_bf16<<<cgrid, blk, 0, stream>>>(k, kb);
    convert_bf16<<<cgrid, blk, 0, stream>>>(v, vb);
    gemm_bt<3><<<dim3(18, 49), blk, 0, stream>>>(qb, kb, vb, wqkvt, bcat,
                                                 qh, kh, vh, nullptr, nullptr,
                                                 T_, 2304, D_, D_, D_, 0, 0,
                                                 nullptr, 0);

    // --- Phase 2: attention split-K flash + combine (emits ctxb bf16) ---
    attn_part<<<dim3(B_ * H_ * 2), blk, 0, stream>>>(qh, kh, vh, part, ml);
    attn_combine<<<dim3((int)(TD / 256)), blk, 0, stream>>>(part, ml, ctxb);

    // --- Phase 3: Wo projection, residual + LN1 (emits xb, zeroes moe) ---
    gemm_bt<0><<<dim3(6, 49), blk, 0, stream>>>(ctxb, nullptr, nullptr, wot, bo,
                                                attnout, nullptr, nullptr, nullptr, nullptr,
                                                T_, D_, D_, D_, D_, 0, 0, nullptr, 0);
    ln_kernel<<<dim3(T_), blk, 0, stream>>>(q, attnout, ln1g, ln1b, x, xb, moe);

    // --- Phase 4: gating ---
    gate_kernel<<<dim3(T_ / 4), blk, 0, stream>>>(x, Wg, bg, gates);

    // --- Phase 5: MoE, expert pairs (z-batched; W2 split-K2 + atomics) ---
    for (int g = 0; g < 4; ++g) {
        const int e0 = 2 * g;
        transpose_to_bf16<<<dim3(F_/64, D_/64, 2), blk, 0, stream>>>(
            W1 + (size_t)e0 * DF, w1t, D_, F_, DF, DF);
        transpose_to_bf16<<<dim3(D_/64, F_/64, 2), blk, 0, stream>>>(
            W2 + (size_t)e0 * DF, w2t, F_, D_, DF, DF);
        // h_e = GELU(x @ W1_e + b1_e), e in {e0, e0+1}
        gemm_bt<1><<<dim3(24, 49, 2), blk, 0, stream>>>(
            xb, nullptr, nullptr, w1t, b1 + (size_t)e0 * F_,
            nullptr, nullptr, nullptr, hb0, hb1,
            T_, F_, D_, D_, D_, DF, F_, nullptr, 0);
        // moe += gate_e * (h_e @ W2_e + b2_e), split-K x2
        gemm_bt<2><<<dim3(6, 49, 4), blk, 0, stream>>>(
            hb0, hb1, nullptr, w2t, b2 + (size_t)e0 * D_,
            moe, nullptr, nullptr, nullptr, nullptr,
            T_, D_, F_ / 2, F_, F_, DF, D_, gates, e0);
    }

    // --- Phase 6: residual + LN2 -> output ---
    ln_kernel<<<dim3(T_), blk, 0, stream>>>(x, moe, ln2g, ln2b, out, nullptr, nullptr);
}